// Round 8
// baseline (336.629 us; speedup 1.0000x reference)
//
#include <hip/hip_runtime.h>
#include <math.h>

#define B_ 2
#define S_ 4096
#define D_ 512
#define H_ 8
#define HD_ 64
#define NROW_ (B_ * S_)
#define NELEM_ ((size_t)NROW_ * D_)   // 4194304
#define WELEM_ ((size_t)D_ * D_)      // 262144

typedef _Float16 half8 __attribute__((ext_vector_type(8)));
typedef _Float16 half4v __attribute__((ext_vector_type(4)));
typedef __fp16 fp16x2 __attribute__((ext_vector_type(2)));   // pkrtz ret type
typedef float floatx4 __attribute__((ext_vector_type(4)));

__device__ __forceinline__ half8 cvt_half8(float4 a, float4 b) {
  fp16x2 l0 = __builtin_amdgcn_cvt_pkrtz(a.x, a.y);
  fp16x2 l1 = __builtin_amdgcn_cvt_pkrtz(a.z, a.w);
  fp16x2 l2 = __builtin_amdgcn_cvt_pkrtz(b.x, b.y);
  fp16x2 l3 = __builtin_amdgcn_cvt_pkrtz(b.z, b.w);
  half8 h;
  h[0] = l0[0]; h[1] = l0[1]; h[2] = l1[0]; h[3] = l1[1];
  h[4] = l2[0]; h[5] = l2[1]; h[6] = l3[0]; h[7] = l3[1];
  return h;
}

// ---------------------------------------------------------------------------
// W[512][512] fp32 -> W^T fp16 (scaled), all 4 weights in one launch (z).
// ---------------------------------------------------------------------------
struct WPtrs { const float *W0, *W1, *W2, *W3; };

__global__ void wT4_kernel(WPtrs p, _Float16* __restrict__ WTbase) {
  __shared__ float tl[32][33];
  const int z = blockIdx.z;
  const float* W = z == 0 ? p.W0 : z == 1 ? p.W1 : z == 2 ? p.W2 : p.W3;
  const float scale = z == 0 ? 0.125f : 1.0f;   // fold 1/sqrt(HD) into Wq
  _Float16* Wt = WTbase + (size_t)z * WELEM_;
  const int t = threadIdx.x;
  const int k0 = blockIdx.y * 32, n0 = blockIdx.x * 32;
  const int r = t >> 3, c0 = (t & 7) * 4;
  const float4 v = *(const float4*)&W[(size_t)(k0 + r) * D_ + n0 + c0];
  tl[r][c0 + 0] = v.x; tl[r][c0 + 1] = v.y;
  tl[r][c0 + 2] = v.z; tl[r][c0 + 3] = v.w;
  __syncthreads();
  half4v hv;
#pragma unroll
  for (int j = 0; j < 4; ++j) hv[j] = (_Float16)(tl[c0 + j][r] * scale);
  *(half4v*)&Wt[(size_t)(n0 + r) * D_ + k0 + c0] = hv;
}

// ---------------------------------------------------------------------------
// V[b][s][h*64+d] fp16 -> VhT[b][h][d][s] fp16 (plain transpose).
// ---------------------------------------------------------------------------
__global__ void vT_kernel(const _Float16* __restrict__ Vh,
                          _Float16* __restrict__ VhT) {
  __shared__ alignas(16) _Float16 T[64][72];
  const int t = threadIdx.x;
  const int s0 = blockIdx.x * 64;
  const int h = blockIdx.y, b = blockIdx.z;
  const int srow = t >> 3, soff = (t & 7) * 8;
#pragma unroll
  for (int i = 0; i < 2; ++i)
    *(half8*)&T[srow + 32 * i][soff] = *(const half8*)
        &Vh[(size_t)(b * S_ + s0 + srow + 32 * i) * D_ + h * HD_ + soff];
  __syncthreads();
  const size_t obase = (size_t)(b * H_ + h) * HD_ * S_;
#pragma unroll
  for (int i = 0; i < 2; ++i) {
    half8 o;
#pragma unroll
    for (int j = 0; j < 8; ++j) o[j] = T[soff + j][srow + 32 * i];
    *(half8*)&VhT[obase + (size_t)(srow + 32 * i) * S_ + s0 + soff] = o;
  }
}

// ---------------------------------------------------------------------------
// MFMA GEMM body (unchanged).
// ---------------------------------------------------------------------------
template <bool AF16, bool OUT16, int BM>
__device__ __forceinline__ void gemm_body(
    const void* __restrict__ Av, const _Float16* __restrict__ Bt,
    const float* __restrict__ bias, void* __restrict__ Cout, float bscale,
    int bx, int by, int tid) {
  constexpr int MT = BM / 32;
  __shared__ alignas(16) _Float16 As[BM][72];
  __shared__ alignas(16) _Float16 Bs[128][72];

  const int w = tid >> 6, lane = tid & 63;
  const int m = lane & 15, quad = lane >> 4;
  const int row0 = by * BM, col0 = bx * 128;
  const int wr = (w >> 1) * (BM / 2), wc = (w & 1) * 64;
  const int srow = tid >> 3, soff = (tid & 7) * 8;

  const _Float16* A16 = (const _Float16*)Av;
  const float* A32 = (const float*)Av;

  floatx4 acc[MT][4];
#pragma unroll
  for (int i = 0; i < MT; ++i)
#pragma unroll
    for (int j = 0; j < 4; ++j) acc[i][j] = floatx4{0.f, 0.f, 0.f, 0.f};

  half8 pa16[MT];
  float4 pa32[MT][2];
  half8 pb[4];
#pragma unroll
  for (int i = 0; i < MT; ++i) {
    const size_t ar = (size_t)(row0 + srow + 32 * i) * D_ + soff;
    if (AF16) pa16[i] = *(const half8*)&A16[ar];
    else { pa32[i][0] = *(const float4*)&A32[ar];
           pa32[i][1] = *(const float4*)&A32[ar + 4]; }
  }
#pragma unroll
  for (int i = 0; i < 4; ++i)
    pb[i] = *(const half8*)&Bt[(size_t)(col0 + srow + 32 * i) * D_ + soff];

  for (int kt = 0; kt < D_ / 64; ++kt) {
    if (kt) __syncthreads();
#pragma unroll
    for (int i = 0; i < MT; ++i)
      *(half8*)&As[srow + 32 * i][soff] =
          AF16 ? pa16[i] : cvt_half8(pa32[i][0], pa32[i][1]);
#pragma unroll
    for (int i = 0; i < 4; ++i) *(half8*)&Bs[srow + 32 * i][soff] = pb[i];
    __syncthreads();
    if (kt < D_ / 64 - 1) {
      const int kc = (kt + 1) * 64 + soff;
#pragma unroll
      for (int i = 0; i < MT; ++i) {
        const size_t ar = (size_t)(row0 + srow + 32 * i) * D_ + kc;
        if (AF16) pa16[i] = *(const half8*)&A16[ar];
        else { pa32[i][0] = *(const float4*)&A32[ar];
               pa32[i][1] = *(const float4*)&A32[ar + 4]; }
      }
#pragma unroll
      for (int i = 0; i < 4; ++i)
        pb[i] = *(const half8*)&Bt[(size_t)(col0 + srow + 32 * i) * D_ + kc];
    }
#pragma unroll
    for (int h = 0; h < 2; ++h) {
      half8 af[MT], bf[4];
#pragma unroll
      for (int mt = 0; mt < MT; ++mt)
        af[mt] = *(const half8*)&As[wr + mt * 16 + m][h * 32 + quad * 8];
#pragma unroll
      for (int nt = 0; nt < 4; ++nt)
        bf[nt] = *(const half8*)&Bs[wc + nt * 16 + m][h * 32 + quad * 8];
#pragma unroll
      for (int mt = 0; mt < MT; ++mt)
#pragma unroll
        for (int nt = 0; nt < 4; ++nt)
          acc[mt][nt] = __builtin_amdgcn_mfma_f32_16x16x32_f16(
              af[mt], bf[nt], acc[mt][nt], 0, 0, 0);
    }
  }

  float bv[4];
#pragma unroll
  for (int nt = 0; nt < 4; ++nt)
    bv[nt] = bias[col0 + wc + nt * 16 + m] * bscale;
#pragma unroll
  for (int mt = 0; mt < MT; ++mt)
#pragma unroll
    for (int nt = 0; nt < 4; ++nt)
#pragma unroll
      for (int r = 0; r < 4; ++r) {
        const int row = row0 + wr + mt * 16 + quad * 4 + r;
        const int col = col0 + wc + nt * 16 + m;
        const float vout = acc[mt][nt][r] + bv[nt];
        if (OUT16)
          ((_Float16*)Cout)[(size_t)row * D_ + col] = (_Float16)vout;
        else
          ((float*)Cout)[(size_t)row * D_ + col] = vout;
      }
}

struct QkvPtrs { const float *A0, *A1, *A2, *b0, *b1, *b2; };

__global__ __launch_bounds__(256, 3) void qkv_gemm_kernel(
    QkvPtrs p, const _Float16* __restrict__ WT, _Float16* __restrict__ Cb) {
  const int z = blockIdx.z;
  const float* A = z == 0 ? p.A0 : z == 1 ? p.A1 : p.A2;
  const float* bias = z == 0 ? p.b0 : z == 1 ? p.b1 : p.b2;
  gemm_body<false, true, 128>(A, WT + (size_t)z * WELEM_, bias,
                              Cb + (size_t)z * NELEM_, z == 0 ? 0.125f : 1.0f,
                              blockIdx.x, blockIdx.y, threadIdx.x);
}

__global__ __launch_bounds__(256, 2) void out_gemm_kernel(
    const _Float16* __restrict__ Oh, const _Float16* __restrict__ WpT,
    const float* __restrict__ bp, float* __restrict__ out) {
  gemm_body<true, false, 64>(Oh, WpT, bp, out, 1.0f, blockIdx.x, blockIdx.y,
                             threadIdx.x);
}

// ---------------------------------------------------------------------------
// Attention v3 = v2 + register double-buffer prefetch (the round-7 regression
// was latency: 6 dependent global loads per iter, waitcnt'd immediately).
// Now tile kt+1's K/V loads are issued BEFORE tile kt's compute; the vmcnt
// wait lands after ~400 cyc of MFMA+VALU -> L2 latency hidden.
// ---------------------------------------------------------------------------
__global__ __launch_bounds__(256, 3) void attn_v2_kernel(
    const _Float16* __restrict__ Qg, const _Float16* __restrict__ Kg,
    const _Float16* __restrict__ VT, _Float16* __restrict__ Og) {
  __shared__ float ored[64][67];   // [d][q] fp32 partial-out reduction
  __shared__ float lred[4][64];    // per-wave row-sum partials

  const int t = threadIdx.x;
  const int w = t >> 6, lane = t & 63;
  const int m = lane & 15, quad = lane >> 4;
  const int q0 = blockIdx.x * 64;
  const size_t base =
      (size_t)blockIdx.z * ((size_t)S_ * D_) + (size_t)blockIdx.y * HD_;
  const size_t vbase = (size_t)(blockIdx.z * H_ + blockIdx.y) * HD_ * S_;

  // ---- Q B-frags, register-resident: B[k=d][n=q], q=q0+16nt+m
  half8 qb[4][2];
#pragma unroll
  for (int nt = 0; nt < 4; ++nt)
#pragma unroll
    for (int hh = 0; hh < 2; ++hh)
      qb[nt][hh] = *(const half8*)
          &Qg[base + (size_t)(q0 + 16 * nt + m) * D_ + 32 * hh + 8 * quad];

  floatx4 oacc[4][4];   // out^T partial: [mt=d-tile][nt=q-tile]
  float lpart[4];
#pragma unroll
  for (int i = 0; i < 4; ++i) {
    lpart[i] = 0.f;
#pragma unroll
    for (int j = 0; j < 4; ++j) oacc[i][j] = floatx4{0.f, 0.f, 0.f, 0.f};
  }
  const floatx4 z4 = floatx4{0.f, 0.f, 0.f, 0.f};

  // this wave's key pointers (16 keys per 64-key tile)
  const _Float16* kp = Kg + base + (size_t)(16 * w + m) * D_ + 8 * quad;
  const _Float16* vp0 = VT + vbase + (size_t)m * S_ + 16 * w + 4 * quad;
  const _Float16* vp1 = vp0 + (size_t)16 * S_;
  const _Float16* vp2 = vp0 + (size_t)32 * S_;
  const _Float16* vp3 = vp0 + (size_t)48 * S_;
  const size_t kstep = (size_t)64 * D_;

  // ---- preload tile 0
  half8 ka0 = *(const half8*)kp;
  half8 ka1 = *(const half8*)(kp + 32);
  half4v va0 = *(const half4v*)vp0;
  half4v va1 = *(const half4v*)vp1;
  half4v va2 = *(const half4v*)vp2;
  half4v va3 = *(const half4v*)vp3;

  for (int kt = 0; kt < S_ / 64; ++kt) {
    // ---- issue next tile's loads FIRST (last iter: re-read tile, discarded)
    if (kt < S_ / 64 - 1) {
      kp += kstep; vp0 += 64; vp1 += 64; vp2 += 64; vp3 += 64;
    }
    const half8 nk0 = *(const half8*)kp;
    const half8 nk1 = *(const half8*)(kp + 32);
    const half4v nv0 = *(const half4v*)vp0;
    const half4v nv1 = *(const half4v*)vp1;
    const half4v nv2 = *(const half4v*)vp2;
    const half4v nv3 = *(const half4v*)vp3;

    // ---- S^T = K.Q^T: sacc[nt]: C[key=quad*4+r][q=16nt+m]
    floatx4 sacc[4];
#pragma unroll
    for (int nt = 0; nt < 4; ++nt) {
      floatx4 s = __builtin_amdgcn_mfma_f32_16x16x32_f16(ka0, qb[nt][0], z4,
                                                         0, 0, 0);
      s = __builtin_amdgcn_mfma_f32_16x16x32_f16(ka1, qb[nt][1], s, 0, 0, 0);
      sacc[nt] = s;
    }

    // ---- softmax numerators -> P^T B-frags (pure registers)
    half4v pbf[4];
#pragma unroll
    for (int nt = 0; nt < 4; ++nt) {
      const float p0 = __expf(fminf(sacc[nt][0], 11.f));
      const float p1 = __expf(fminf(sacc[nt][1], 11.f));
      const float p2 = __expf(fminf(sacc[nt][2], 11.f));
      const float p3 = __expf(fminf(sacc[nt][3], 11.f));
      lpart[nt] += (p0 + p1) + (p2 + p3);
      const fp16x2 lo = __builtin_amdgcn_cvt_pkrtz(p0, p1);
      const fp16x2 hi = __builtin_amdgcn_cvt_pkrtz(p2, p3);
      half4v pb;
      pb[0] = lo[0]; pb[1] = lo[1]; pb[2] = hi[0]; pb[3] = hi[1];
      pbf[nt] = pb;
    }

    // ---- out^T += V^T . P^T (K=16 MFMA, operands all in registers)
#pragma unroll
    for (int nt = 0; nt < 4; ++nt) {
      oacc[0][nt] = __builtin_amdgcn_mfma_f32_16x16x16f16(
          va0, pbf[nt], oacc[0][nt], 0, 0, 0);
      oacc[1][nt] = __builtin_amdgcn_mfma_f32_16x16x16f16(
          va1, pbf[nt], oacc[1][nt], 0, 0, 0);
      oacc[2][nt] = __builtin_amdgcn_mfma_f32_16x16x16f16(
          va2, pbf[nt], oacc[2][nt], 0, 0, 0);
      oacc[3][nt] = __builtin_amdgcn_mfma_f32_16x16x16f16(
          va3, pbf[nt], oacc[3][nt], 0, 0, 0);
    }

    // ---- consume prefetch
    ka0 = nk0; ka1 = nk1;
    va0 = nv0; va1 = nv1; va2 = nv2; va3 = nv3;
  }

  // ---- epilogue: reduce across quads (keys within wave), then across waves
#pragma unroll
  for (int nt = 0; nt < 4; ++nt) {
    float v = lpart[nt];
    v += __shfl_xor(v, 16);
    v += __shfl_xor(v, 32);
    lpart[nt] = v;
  }
  if (quad == 0) {
#pragma unroll
    for (int nt = 0; nt < 4; ++nt) lred[w][16 * nt + m] = lpart[nt];
  }

  for (int wv = 0; wv < 4; ++wv) {
    if (w == wv) {
#pragma unroll
      for (int mt = 0; mt < 4; ++mt)
#pragma unroll
        for (int nt = 0; nt < 4; ++nt)
#pragma unroll
          for (int r = 0; r < 4; ++r) {
            const int d = 16 * mt + 4 * quad + r;
            const int qq = 16 * nt + m;
            float v = oacc[mt][nt][r];
            if (wv) v += ored[d][qq];
            ored[d][qq] = v;
          }
    }
    __syncthreads();
  }

  // ---- normalize + write: thread t -> q = t>>2, d-group = (t&3)*16
  const int qq = t >> 2, dg = (t & 3) * 16;
  const float li =
      1.0f / (lred[0][qq] + lred[1][qq] + lred[2][qq] + lred[3][qq]);
  half8 o0, o1;
#pragma unroll
  for (int j = 0; j < 8; ++j) {
    o0[j] = (_Float16)(ored[dg + j][qq] * li);
    o1[j] = (_Float16)(ored[dg + 8 + j][qq] * li);
  }
  _Float16* op = Og + base + (size_t)(q0 + qq) * D_ + dg;
  *(half8*)op = o0;
  *(half8*)(op + 8) = o1;
}

// ---------------------------------------------------------------------------
extern "C" void kernel_launch(void* const* d_in, const int* in_sizes, int n_in,
                              void* d_out, int out_size, void* d_ws,
                              size_t ws_size, hipStream_t stream) {
  const float* x  = (const float*)d_in[0];
  const float* y  = (const float*)d_in[1];
  const float* z  = (const float*)d_in[2];
  const float* Wq = (const float*)d_in[3];
  const float* bq = (const float*)d_in[4];
  const float* Wk = (const float*)d_in[5];
  const float* bk = (const float*)d_in[6];
  const float* Wv = (const float*)d_in[7];
  const float* bv = (const float*)d_in[8];
  const float* Wp = (const float*)d_in[9];
  const float* bp = (const float*)d_in[10];

  _Float16* hws = (_Float16*)d_ws;
  _Float16* WT  = hws;                      // 4 x WELEM (q,k,v,p)
  _Float16* Qh  = WT + 4 * WELEM_;
  _Float16* Kh  = Qh + NELEM_;
  _Float16* Vh  = Kh + NELEM_;
  _Float16* Oh  = Vh + NELEM_;
  _Float16* VhT = Oh + NELEM_;

  WPtrs wp{Wq, Wk, Wv, Wp};
  wT4_kernel<<<dim3(16, 16, 4), 256, 0, stream>>>(wp, WT);

  QkvPtrs qp{x, y, z, bq, bk, bv};
  qkv_gemm_kernel<<<dim3(4, 64, 3), 256, 0, stream>>>(qp, WT, Qh);

  vT_kernel<<<dim3(S_ / 64, H_, B_), 256, 0, stream>>>(Vh, VhT);

  attn_v2_kernel<<<dim3(S_ / 64, H_, B_), 256, 0, stream>>>(Qh, Kh, VhT, Oh);

  out_gemm_kernel<<<dim3(4, 128), 256, 0, stream>>>(Oh, WT + 3 * WELEM_, bp,
                                                    (float*)d_out);
}

// Round 9
// 290.451 us; speedup vs baseline: 1.1590x; 1.1590x over previous
//
#include <hip/hip_runtime.h>
#include <math.h>

#define B_ 2
#define S_ 4096
#define D_ 512
#define H_ 8
#define HD_ 64
#define NROW_ (B_ * S_)
#define NELEM_ ((size_t)NROW_ * D_)   // 4194304
#define WELEM_ ((size_t)D_ * D_)      // 262144
#define QSC 0.18033688f               // 0.125 * log2(e): softmax via exp2

typedef _Float16 half8 __attribute__((ext_vector_type(8)));
typedef _Float16 half4v __attribute__((ext_vector_type(4)));
typedef __fp16 fp16x2 __attribute__((ext_vector_type(2)));   // pkrtz ret type
typedef float floatx4 __attribute__((ext_vector_type(4)));

__device__ __forceinline__ half8 cvt_half8(float4 a, float4 b) {
  fp16x2 l0 = __builtin_amdgcn_cvt_pkrtz(a.x, a.y);
  fp16x2 l1 = __builtin_amdgcn_cvt_pkrtz(a.z, a.w);
  fp16x2 l2 = __builtin_amdgcn_cvt_pkrtz(b.x, b.y);
  fp16x2 l3 = __builtin_amdgcn_cvt_pkrtz(b.z, b.w);
  half8 h;
  h[0] = l0[0]; h[1] = l0[1]; h[2] = l1[0]; h[3] = l1[1];
  h[4] = l2[0]; h[5] = l2[1]; h[6] = l3[0]; h[7] = l3[1];
  return h;
}

// async 16B/lane global -> LDS (lds dest = wave-uniform base + 16*lane)
__device__ __forceinline__ void async_lds16(const _Float16* g,
                                            _Float16* l) {
  __builtin_amdgcn_global_load_lds(
      (const __attribute__((address_space(1))) void*)g,
      (__attribute__((address_space(3))) void*)l, 16, 0, 0);
}

// ---------------------------------------------------------------------------
// W[512][512] fp32 -> W^T fp16 (scaled), all 4 weights in one launch (z).
// ---------------------------------------------------------------------------
struct WPtrs { const float *W0, *W1, *W2, *W3; };

__global__ void wT4_kernel(WPtrs p, _Float16* __restrict__ WTbase) {
  __shared__ float tl[32][33];
  const int z = blockIdx.z;
  const float* W = z == 0 ? p.W0 : z == 1 ? p.W1 : z == 2 ? p.W2 : p.W3;
  const float scale = z == 0 ? QSC : 1.0f;   // fold 0.125*log2e into Wq
  _Float16* Wt = WTbase + (size_t)z * WELEM_;
  const int t = threadIdx.x;
  const int k0 = blockIdx.y * 32, n0 = blockIdx.x * 32;
  const int r = t >> 3, c0 = (t & 7) * 4;
  const float4 v = *(const float4*)&W[(size_t)(k0 + r) * D_ + n0 + c0];
  tl[r][c0 + 0] = v.x; tl[r][c0 + 1] = v.y;
  tl[r][c0 + 2] = v.z; tl[r][c0 + 3] = v.w;
  __syncthreads();
  half4v hv;
#pragma unroll
  for (int j = 0; j < 4; ++j) hv[j] = (_Float16)(tl[c0 + j][r] * scale);
  *(half4v*)&Wt[(size_t)(n0 + r) * D_ + k0 + c0] = hv;
}

// ---------------------------------------------------------------------------
// V[b][s][h*64+d] fp16 -> VhT[b][h][d][s] fp16 (plain transpose).
// ---------------------------------------------------------------------------
__global__ void vT_kernel(const _Float16* __restrict__ Vh,
                          _Float16* __restrict__ VhT) {
  __shared__ alignas(16) _Float16 T[64][72];
  const int t = threadIdx.x;
  const int s0 = blockIdx.x * 64;
  const int h = blockIdx.y, b = blockIdx.z;
  const int srow = t >> 3, soff = (t & 7) * 8;
#pragma unroll
  for (int i = 0; i < 2; ++i)
    *(half8*)&T[srow + 32 * i][soff] = *(const half8*)
        &Vh[(size_t)(b * S_ + s0 + srow + 32 * i) * D_ + h * HD_ + soff];
  __syncthreads();
  const size_t obase = (size_t)(b * H_ + h) * HD_ * S_;
#pragma unroll
  for (int i = 0; i < 2; ++i) {
    half8 o;
#pragma unroll
    for (int j = 0; j < 8; ++j) o[j] = T[soff + j][srow + 32 * i];
    *(half8*)&VhT[obase + (size_t)(srow + 32 * i) * S_ + s0 + soff] = o;
  }
}

// ---------------------------------------------------------------------------
// MFMA GEMM body (unchanged).
// ---------------------------------------------------------------------------
template <bool AF16, bool OUT16, int BM>
__device__ __forceinline__ void gemm_body(
    const void* __restrict__ Av, const _Float16* __restrict__ Bt,
    const float* __restrict__ bias, void* __restrict__ Cout, float bscale,
    int bx, int by, int tid) {
  constexpr int MT = BM / 32;
  __shared__ alignas(16) _Float16 As[BM][72];
  __shared__ alignas(16) _Float16 Bs[128][72];

  const int w = tid >> 6, lane = tid & 63;
  const int m = lane & 15, quad = lane >> 4;
  const int row0 = by * BM, col0 = bx * 128;
  const int wr = (w >> 1) * (BM / 2), wc = (w & 1) * 64;
  const int srow = tid >> 3, soff = (tid & 7) * 8;

  const _Float16* A16 = (const _Float16*)Av;
  const float* A32 = (const float*)Av;

  floatx4 acc[MT][4];
#pragma unroll
  for (int i = 0; i < MT; ++i)
#pragma unroll
    for (int j = 0; j < 4; ++j) acc[i][j] = floatx4{0.f, 0.f, 0.f, 0.f};

  half8 pa16[MT];
  float4 pa32[MT][2];
  half8 pb[4];
#pragma unroll
  for (int i = 0; i < MT; ++i) {
    const size_t ar = (size_t)(row0 + srow + 32 * i) * D_ + soff;
    if (AF16) pa16[i] = *(const half8*)&A16[ar];
    else { pa32[i][0] = *(const float4*)&A32[ar];
           pa32[i][1] = *(const float4*)&A32[ar + 4]; }
  }
#pragma unroll
  for (int i = 0; i < 4; ++i)
    pb[i] = *(const half8*)&Bt[(size_t)(col0 + srow + 32 * i) * D_ + soff];

  for (int kt = 0; kt < D_ / 64; ++kt) {
    if (kt) __syncthreads();
#pragma unroll
    for (int i = 0; i < MT; ++i)
      *(half8*)&As[srow + 32 * i][soff] =
          AF16 ? pa16[i] : cvt_half8(pa32[i][0], pa32[i][1]);
#pragma unroll
    for (int i = 0; i < 4; ++i) *(half8*)&Bs[srow + 32 * i][soff] = pb[i];
    __syncthreads();
    if (kt < D_ / 64 - 1) {
      const int kc = (kt + 1) * 64 + soff;
#pragma unroll
      for (int i = 0; i < MT; ++i) {
        const size_t ar = (size_t)(row0 + srow + 32 * i) * D_ + kc;
        if (AF16) pa16[i] = *(const half8*)&A16[ar];
        else { pa32[i][0] = *(const float4*)&A32[ar];
               pa32[i][1] = *(const float4*)&A32[ar + 4]; }
      }
#pragma unroll
      for (int i = 0; i < 4; ++i)
        pb[i] = *(const half8*)&Bt[(size_t)(col0 + srow + 32 * i) * D_ + kc];
    }
#pragma unroll
    for (int h = 0; h < 2; ++h) {
      half8 af[MT], bf[4];
#pragma unroll
      for (int mt = 0; mt < MT; ++mt)
        af[mt] = *(const half8*)&As[wr + mt * 16 + m][h * 32 + quad * 8];
#pragma unroll
      for (int nt = 0; nt < 4; ++nt)
        bf[nt] = *(const half8*)&Bs[wc + nt * 16 + m][h * 32 + quad * 8];
#pragma unroll
      for (int mt = 0; mt < MT; ++mt)
#pragma unroll
        for (int nt = 0; nt < 4; ++nt)
          acc[mt][nt] = __builtin_amdgcn_mfma_f32_16x16x32_f16(
              af[mt], bf[nt], acc[mt][nt], 0, 0, 0);
    }
  }

  float bv[4];
#pragma unroll
  for (int nt = 0; nt < 4; ++nt)
    bv[nt] = bias[col0 + wc + nt * 16 + m] * bscale;
#pragma unroll
  for (int mt = 0; mt < MT; ++mt)
#pragma unroll
    for (int nt = 0; nt < 4; ++nt)
#pragma unroll
      for (int r = 0; r < 4; ++r) {
        const int row = row0 + wr + mt * 16 + quad * 4 + r;
        const int col = col0 + wc + nt * 16 + m;
        const float vout = acc[mt][nt][r] + bv[nt];
        if (OUT16)
          ((_Float16*)Cout)[(size_t)row * D_ + col] = (_Float16)vout;
        else
          ((float*)Cout)[(size_t)row * D_ + col] = vout;
      }
}

struct QkvPtrs { const float *A0, *A1, *A2, *b0, *b1, *b2; };

__global__ __launch_bounds__(256, 3) void qkv_gemm_kernel(
    QkvPtrs p, const _Float16* __restrict__ WT, _Float16* __restrict__ Cb) {
  const int z = blockIdx.z;
  const float* A = z == 0 ? p.A0 : z == 1 ? p.A1 : p.A2;
  const float* bias = z == 0 ? p.b0 : z == 1 ? p.b1 : p.b2;
  gemm_body<false, true, 128>(A, WT + (size_t)z * WELEM_, bias,
                              Cb + (size_t)z * NELEM_, z == 0 ? QSC : 1.0f,
                              blockIdx.x, blockIdx.y, threadIdx.x);
}

__global__ __launch_bounds__(256, 2) void out_gemm_kernel(
    const _Float16* __restrict__ Oh, const _Float16* __restrict__ WpT,
    const float* __restrict__ bp, float* __restrict__ out) {
  gemm_body<true, false, 64>(Oh, WpT, bp, out, 1.0f, blockIdx.x, blockIdx.y,
                             threadIdx.x);
}

// ---------------------------------------------------------------------------
// Attention v4: v2's register-P pipeline + coalesced async LDS staging.
// Round-8 finding: per-lane row-scatter global loads (16 cache lines per
// instruction) bound the loop on L2 transactions. Now K rows / V^T rows are
// staged coalesced via global_load_lds (16B/lane) into XOR-swizzled LDS
// (slot = chunk ^ (row&7); global_load_lds forbids padding), double-buffered,
// ONE barrier per tile. Frag ds_reads are 2 lanes/bank (free). Softmax via
// native exp2 (log2e folded into Wq). Waves split keys (16 each); P^T flows
// S^T-C-layout -> PV-B-frag entirely in registers (validated r7/r8).
// ---------------------------------------------------------------------------
__global__ __launch_bounds__(256, 3) void attn_v4_kernel(
    const _Float16* __restrict__ Qg, const _Float16* __restrict__ Kg,
    const _Float16* __restrict__ VT, _Float16* __restrict__ Og) {
  // smem[0..1] = K tile dbuf, smem[2..3] = V^T tile dbuf (each 64x64 f16=8KB)
  __shared__ alignas(16) _Float16 smem[4][64 * 64];

  const int t = threadIdx.x;
  const int w = t >> 6, lane = t & 63;
  const int m = lane & 15, quad = lane >> 4;
  const int q0 = blockIdx.x * 64;
  const size_t base =
      (size_t)blockIdx.z * ((size_t)S_ * D_) + (size_t)blockIdx.y * HD_;
  const size_t vbase = (size_t)(blockIdx.z * H_ + blockIdx.y) * HD_ * S_;

  // ---- Q B-frags, register-resident: B[k=d][n=q], q=q0+16nt+m
  half8 qb[4][2];
#pragma unroll
  for (int nt = 0; nt < 4; ++nt)
#pragma unroll
    for (int hh = 0; hh < 2; ++hh)
      qb[nt][hh] = *(const half8*)
          &Qg[base + (size_t)(q0 + 16 * nt + m) * D_ + 32 * hh + 8 * quad];

  floatx4 oacc[4][4];
  float lpart[4];
#pragma unroll
  for (int i = 0; i < 4; ++i) {
    lpart[i] = 0.f;
#pragma unroll
    for (int j = 0; j < 4; ++j) oacc[i][j] = floatx4{0.f, 0.f, 0.f, 0.f};
  }
  const floatx4 z4 = floatx4{0.f, 0.f, 0.f, 0.f};

  // ---- staging source pointers (this wave stages rows 16w..16w+15 of K
  //      and of V^T, 2 issues of 8 rows x 128B, chunk-swizzled)
  const int sr = lane >> 3;          // row within 8-row issue
  const int sc = lane & 7;           // chunk slot
  const int r0 = 16 * w + sr, r1 = r0 + 8;
  const _Float16* kg0 = Kg + base + (size_t)r0 * D_ + ((sc ^ (r0 & 7)) * 8);
  const _Float16* kg1 = Kg + base + (size_t)r1 * D_ + ((sc ^ (r1 & 7)) * 8);
  const _Float16* vg0 = VT + vbase + (size_t)r0 * S_ + ((sc ^ (r0 & 7)) * 8);
  const _Float16* vg1 = VT + vbase + (size_t)r1 * S_ + ((sc ^ (r1 & 7)) * 8);
  const size_t kstep = (size_t)64 * D_;
  const int ld0 = (16 * w) * 64, ld1 = ld0 + 512;   // LDS elt offsets

  // ---- prologue: stage tile 0 into buf 0
  async_lds16(kg0, &smem[0][ld0]);
  async_lds16(kg1, &smem[0][ld1]);
  async_lds16(vg0, &smem[2][ld0]);
  async_lds16(vg1, &smem[2][ld1]);
  kg0 += kstep; kg1 += kstep; vg0 += 64; vg1 += 64;
  __syncthreads();

  const int mx7 = m & 7;
  const int ka0_off = (16 * w + m) * 64 + ((quad ^ mx7) << 3);
  const int ka1_off = (16 * w + m) * 64 + (((4 + quad) ^ mx7) << 3);
  const int vck = 2 * w + (quad >> 1);
  const int va_off = (((vck ^ mx7) << 3) + 4 * (quad & 1)) + m * 64;

  for (int kt = 0; kt < S_ / 64; ++kt) {
    const int buf = kt & 1;
    const _Float16* kb = &smem[buf][0];
    const _Float16* vb = &smem[2 + buf][0];

    // ---- frag ds_reads FIRST (data staged last iter; vmcnt drained at barrier)
    const half8 ka0 = *(const half8*)(kb + ka0_off);
    const half8 ka1 = *(const half8*)(kb + ka1_off);
    half4v va[4];
#pragma unroll
    for (int mt = 0; mt < 4; ++mt)
      va[mt] = *(const half4v*)(vb + va_off + mt * 16 * 64);

    // ---- async stage next tile into other buffer
    if (kt < S_ / 64 - 1) {
      _Float16* kn = &smem[buf ^ 1][0];
      _Float16* vn = &smem[2 + (buf ^ 1)][0];
      async_lds16(kg0, kn + ld0);
      async_lds16(kg1, kn + ld1);
      async_lds16(vg0, vn + ld0);
      async_lds16(vg1, vn + ld1);
      kg0 += kstep; kg1 += kstep; vg0 += 64; vg1 += 64;
    }

    // ---- S^T = K.Q^T: sacc[nt]: C[key=quad*4+r][q=16nt+m]
    floatx4 sacc[4];
#pragma unroll
    for (int nt = 0; nt < 4; ++nt) {
      floatx4 s = __builtin_amdgcn_mfma_f32_16x16x32_f16(ka0, qb[nt][0], z4,
                                                         0, 0, 0);
      s = __builtin_amdgcn_mfma_f32_16x16x32_f16(ka1, qb[nt][1], s, 0, 0, 0);
      sacc[nt] = s;
    }

    // ---- softmax numerators via native exp2 -> P^T B-frags (registers)
    half4v pbf[4];
#pragma unroll
    for (int nt = 0; nt < 4; ++nt) {
      const float p0 = exp2f(fminf(sacc[nt][0], 15.5f));
      const float p1 = exp2f(fminf(sacc[nt][1], 15.5f));
      const float p2 = exp2f(fminf(sacc[nt][2], 15.5f));
      const float p3 = exp2f(fminf(sacc[nt][3], 15.5f));
      lpart[nt] += (p0 + p1) + (p2 + p3);
      const fp16x2 lo = __builtin_amdgcn_cvt_pkrtz(p0, p1);
      const fp16x2 hi = __builtin_amdgcn_cvt_pkrtz(p2, p3);
      half4v pb;
      pb[0] = lo[0]; pb[1] = lo[1]; pb[2] = hi[0]; pb[3] = hi[1];
      pbf[nt] = pb;
    }

    // ---- out^T += V^T . P^T (K=16 MFMA, operands all in registers)
#pragma unroll
    for (int mt = 0; mt < 4; ++mt)
#pragma unroll
      for (int nt = 0; nt < 4; ++nt)
        oacc[mt][nt] = __builtin_amdgcn_mfma_f32_16x16x16f16(
            va[mt], pbf[nt], oacc[mt][nt], 0, 0, 0);

    __syncthreads();   // all waves done with buf; next tile's staging drained
  }

  // ---- epilogue: alias staging LDS for cross-wave reduction
  float* ored = (float*)&smem[0][0];     // [64][67]
  float* lred = ored + 64 * 67;          // [4][64]

#pragma unroll
  for (int nt = 0; nt < 4; ++nt) {
    float v = lpart[nt];
    v += __shfl_xor(v, 16);
    v += __shfl_xor(v, 32);
    lpart[nt] = v;
  }
  if (quad == 0) {
#pragma unroll
    for (int nt = 0; nt < 4; ++nt) lred[w * 64 + 16 * nt + m] = lpart[nt];
  }

  for (int wv = 0; wv < 4; ++wv) {
    if (w == wv) {
#pragma unroll
      for (int mt = 0; mt < 4; ++mt)
#pragma unroll
        for (int nt = 0; nt < 4; ++nt)
#pragma unroll
          for (int r = 0; r < 4; ++r) {
            const int d = 16 * mt + 4 * quad + r;
            const int qq = 16 * nt + m;
            float v = oacc[mt][nt][r];
            if (wv) v += ored[d * 67 + qq];
            ored[d * 67 + qq] = v;
          }
    }
    __syncthreads();
  }

  // ---- normalize + write: thread t -> q = t>>2, d-group = (t&3)*16
  const int qq = t >> 2, dg = (t & 3) * 16;
  const float li = 1.0f / (lred[qq] + lred[64 + qq] + lred[128 + qq] +
                           lred[192 + qq]);
  half8 o0, o1;
#pragma unroll
  for (int j = 0; j < 8; ++j) {
    o0[j] = (_Float16)(ored[(dg + j) * 67 + qq] * li);
    o1[j] = (_Float16)(ored[(dg + 8 + j) * 67 + qq] * li);
  }
  _Float16* op = Og + base + (size_t)(q0 + qq) * D_ + dg;
  *(half8*)op = o0;
  *(half8*)(op + 8) = o1;
}

// ---------------------------------------------------------------------------
extern "C" void kernel_launch(void* const* d_in, const int* in_sizes, int n_in,
                              void* d_out, int out_size, void* d_ws,
                              size_t ws_size, hipStream_t stream) {
  const float* x  = (const float*)d_in[0];
  const float* y  = (const float*)d_in[1];
  const float* z  = (const float*)d_in[2];
  const float* Wq = (const float*)d_in[3];
  const float* bq = (const float*)d_in[4];
  const float* Wk = (const float*)d_in[5];
  const float* bk = (const float*)d_in[6];
  const float* Wv = (const float*)d_in[7];
  const float* bv = (const float*)d_in[8];
  const float* Wp = (const float*)d_in[9];
  const float* bp = (const float*)d_in[10];

  _Float16* hws = (_Float16*)d_ws;
  _Float16* WT  = hws;                      // 4 x WELEM (q,k,v,p)
  _Float16* Qh  = WT + 4 * WELEM_;
  _Float16* Kh  = Qh + NELEM_;
  _Float16* Vh  = Kh + NELEM_;
  _Float16* Oh  = Vh + NELEM_;
  _Float16* VhT = Oh + NELEM_;

  WPtrs wp{Wq, Wk, Wv, Wp};
  wT4_kernel<<<dim3(16, 16, 4), 256, 0, stream>>>(wp, WT);

  QkvPtrs qp{x, y, z, bq, bk, bv};
  qkv_gemm_kernel<<<dim3(4, 64, 3), 256, 0, stream>>>(qp, WT, Qh);

  vT_kernel<<<dim3(S_ / 64, H_, B_), 256, 0, stream>>>(Vh, VhT);

  attn_v4_kernel<<<dim3(S_ / 64, H_, B_), 256, 0, stream>>>(Qh, Kh, VhT, Oh);

  out_gemm_kernel<<<dim3(4, 128), 256, 0, stream>>>(Oh, WT + 3 * WELEM_, bp,
                                                    (float*)d_out);
}